// Round 2
// baseline (311.025 us; speedup 1.0000x reference)
//
#include <hip/hip_runtime.h>

// SepConv: out[b,c,i,j] = sum_{u,v} img[b,c,i+u,j+v] * vert[b,u,i,j] * hori[b,v,i,j]
// B=8, C=3, W=H=512, K=13, Wo=Ho=500.
//
// R2: latency-bound fix. Per block = one (b,i) output row, all 500 j, all 3
// channels (threadIdx.y = c). Weights vert/hori [13][500] for this (b,i) are
// bulk-staged into LDS (52 KB) as one batch of independent float4 loads
// (one latency drain, not 26 serialized per-thread loads). Main loop reads
// weights from LDS, img from L1-warm global (adjacent lanes overlap 12/16B).

#define KK 13
#define NB 8
#define NC 3
#define IW 512
#define IH 512
#define WO 500
#define HO 500
#define QROW 125              // float4 quads per 500-col row
#define NTHREADS 384          // 128 j-quad lanes x 3 channels

__global__ __launch_bounds__(NTHREADS) void sepconv_kernel(
    const float* __restrict__ img,
    const float* __restrict__ hori,
    const float* __restrict__ vert,
    float* __restrict__ out)
{
    __shared__ float4 s_vert[KK * QROW];   // [u][quad], 26 KB
    __shared__ float4 s_hori[KK * QROW];   // [v][quad], 26 KB

    const int tid = threadIdx.y * 128 + threadIdx.x;   // 0..383
    const int i = blockIdx.y;
    const int b = blockIdx.z;

    const size_t khw = (size_t)WO * HO;                 // 250000
    const size_t rowstride4 = khw / 4;                  // 62500 float4s between u-rows
    const float4* vsrc = (const float4*)(vert + (size_t)b * KK * khw + (size_t)i * HO);
    const float4* hsrc = (const float4*)(hori + (size_t)b * KK * khw + (size_t)i * HO);

    // Bulk stage: 13*125 = 1625 float4s per array; ~4.2 per thread, all
    // independent -> single vmcnt drain amortized over the whole batch.
    #pragma unroll
    for (int f = tid; f < KK * QROW; f += NTHREADS) {
        const int u = f / QROW;            // magic-mul, cheap
        const int q = f - u * QROW;
        s_vert[f] = vsrc[(size_t)u * rowstride4 + q];
        s_hori[f] = hsrc[(size_t)u * rowstride4 + q];
    }
    __syncthreads();

    const int tj = threadIdx.x;            // j-quad
    const int c  = threadIdx.y;            // channel
    if (tj >= QROW) return;                // no further barriers; safe
    const int j0 = tj * 4;

    const float* ibase = img + (((size_t)(b * NC + c) * IW) + i) * IH + j0;

    float tmp[4][KK];
    #pragma unroll
    for (int jq = 0; jq < 4; ++jq)
        #pragma unroll
        for (int v = 0; v < KK; ++v)
            tmp[jq][v] = 0.0f;

    #pragma unroll
    for (int u = 0; u < KK; ++u) {
        const float* rp = ibase + (size_t)u * IH;
        const float4 r0 = *(const float4*)(rp + 0);
        const float4 r1 = *(const float4*)(rp + 4);
        const float4 r2 = *(const float4*)(rp + 8);
        const float4 r3 = *(const float4*)(rp + 12);
        const float4 vt = s_vert[u * QROW + tj];

        float row[16];
        row[0]  = r0.x; row[1]  = r0.y; row[2]  = r0.z; row[3]  = r0.w;
        row[4]  = r1.x; row[5]  = r1.y; row[6]  = r1.z; row[7]  = r1.w;
        row[8]  = r2.x; row[9]  = r2.y; row[10] = r2.z; row[11] = r2.w;
        row[12] = r3.x; row[13] = r3.y; row[14] = r3.z; row[15] = r3.w;

        #pragma unroll
        for (int v = 0; v < KK; ++v) {
            tmp[0][v] += row[0 + v] * vt.x;
            tmp[1][v] += row[1 + v] * vt.y;
            tmp[2][v] += row[2 + v] * vt.z;
            tmp[3][v] += row[3 + v] * vt.w;
        }
    }

    float4 o = make_float4(0.f, 0.f, 0.f, 0.f);
    #pragma unroll
    for (int v = 0; v < KK; ++v) {
        const float4 hv = s_hori[v * QROW + tj];
        o.x += tmp[0][v] * hv.x;
        o.y += tmp[1][v] * hv.y;
        o.z += tmp[2][v] * hv.z;
        o.w += tmp[3][v] * hv.w;
    }

    float* op = out + (((size_t)(b * NC + c) * WO) + i) * HO + j0;
    *(float4*)op = o;
}

extern "C" void kernel_launch(void* const* d_in, const int* in_sizes, int n_in,
                              void* d_out, int out_size, void* d_ws, size_t ws_size,
                              hipStream_t stream) {
    const float* img  = (const float*)d_in[0];
    const float* hori = (const float*)d_in[1];
    const float* vert = (const float*)d_in[2];
    float* out = (float*)d_out;

    dim3 block(128, 3, 1);        // x = j-quads (125 used), y = channel
    dim3 grid(1, WO, NB);         // y = output row i, z = batch
    hipLaunchKernelGGL(sepconv_kernel, grid, block, 0, stream, img, hori, vert, out);
}